// Round 5
// baseline (296.321 us; speedup 1.0000x reference)
//
#include <hip/hip_runtime.h>
#include <math.h>

// Problem constants (from reference)
#define BATCH 4
#define N_ANCHORS 211200
#define CHANNELS 256
#define FM_H 200
#define FM_W 176
#define NKP 4096
#define PLANE (FM_H * FM_W)                   // 35200 floats

#define BOXES_ELEMS (BATCH * N_ANCHORS * 7)   // 5,913,600

// BEV: 40 y-strips of 5 rows per plane; each staged strip = 6 rows (overlap
// row for the y+1 tap). Strip buffer padded to 320 float4 (5 GLL/lane * 64
// lanes) = 5120 B. Each WAVE owns 10 strips with a private double buffer:
// LDS = 4 waves * 2 * 5120 = 40960 B -> exactly 4 blocks/CU, 16 waves/CU.
// No block barriers anywhere: the GLL producer and the LDS consumer are the
// same wave, so per-wave counted vmcnt is the only sync needed.
#define QSTRIPS 40
#define ROWS_PER_STRIP 5
#define STRIP_V4 264                          // 6 rows * 44 float4
#define STRIP_V4_LAST 220                     // strip 39: 5 rows only
#define BUF_V4 320                            // padded per-buffer size
#define WAVES 4
#define STRIPS_PER_WAVE 10
#define NBUCKET (BATCH * QSTRIPS)             // 160
#define BUCKET_CAP 512                        // ~102 avg records/bucket

// Decode: barrier-free register streaming, 4 boxes/thread, 1024 boxes/block.
#define DEC_BLOCKS (BATCH * N_ANCHORS / 1024) // 825 exactly

// Async global->LDS, 16B/lane (wave-uniform LDS base + lane*16; staging index
// is lane-linear per wave so the linear layout matches).
#define GLL(g, l) __builtin_amdgcn_global_load_lds(                        \
    (const __attribute__((address_space(1))) void*)(g),                    \
    (__attribute__((address_space(3))) void*)(l), 16, 0, 0)

// ---------------------------------------------------------------------------
// Kernel 1: keypoint transform + bucketing into 40 strips/batch. One block
// per batch (4 x 1024 threads, 4 kp/thread); ranks via LDS atomics only —
// block == batch, so no global atomics and no memset needed.
// Record (16 B): meta = a0 | dx<<10 | dy<<11 | k<<12, wx, WY0, WY1 where
//   a0 = strip-local tap addr (rowoff*176 + x0, rowoff in [0,4], 10 bits)
//   dx = x1-valid (adds 1 col), dy = y1-valid (adds 176)
//   WY0 = (1-wy)*fy0, WY1 = wy*dy   (row-valid flags folded into weights).
// Masked taps re-read the unmasked address, so staged-garbage LDS is never
// dereferenced (no 0*NaN hazard).
// ---------------------------------------------------------------------------
__global__ __launch_bounds__(1024) void kp_transform_kernel(
    const float* __restrict__ kp,        // [B, K, 3]
    int* __restrict__ counts,            // [160]
    float4* __restrict__ bucket)         // [160 * BUCKET_CAP]
{
    __shared__ int lcnt[QSTRIPS];
    const int b   = blockIdx.x;
    const int tid = threadIdx.x;
    if (tid < QSTRIPS) lcnt[tid] = 0;
    __syncthreads();

    // 4 keypoints = 12 consecutive floats = 3 float4.
    const float4* kp4 = (const float4*)(kp + (size_t)b * NKP * 3) + tid * 3;
    float4 p0 = kp4[0], p1 = kp4[1], p2 = kp4[2];
    float kxJ[4] = {p0.x, p0.w, p1.z, p2.y};
    float kyJ[4] = {p0.y, p1.x, p1.w, p2.z};

#pragma unroll
    for (int j = 0; j < 4; ++j) {
        const int k = tid * 4 + j;
        // Verbatim transform math (keeps absmax behavior).
        float ix_idx = kxJ[j] / 0.4f;
        float iy_idx = (kyJ[j] + 40.0f) / 0.4f;
        ix_idx = fminf(fmaxf(ix_idx, 0.0f), (float)(FM_W - 1));
        iy_idx = fminf(fmaxf(iy_idx, 0.0f), (float)(FM_H - 1));
        float nx = 2.0f * (ix_idx / (float)(FM_W - 2)) - 1.0f;
        float ny = 2.0f * (iy_idx / (float)(FM_H - 2)) - 1.0f;
        // grid flip: width coord gets ny, height coord gets nx
        float ix = (ny + 1.0f) * 0.5f * (float)(FM_W - 1);
        float iy = (nx + 1.0f) * 0.5f * (float)(FM_H - 1);

        float x0f = floorf(ix);
        float y0f = floorf(iy);
        float wx = ix - x0f;
        float wy = iy - y0f;
        int x0 = (int)x0f;      // in [0, 175]
        int y0 = (int)y0f;      // in [0, 200] (200 = fully masked row)

        int q = min(y0 / ROWS_PER_STRIP, QSTRIPS - 1);
        int yc0 = min(y0, FM_H - 1);
        int rowoff = yc0 - q * ROWS_PER_STRIP;          // [0, 4]
        int dx = (x0 + 1 <= FM_W - 1) ? 1 : 0;
        int dy = (y0 + 1 <= FM_H - 1) ? 1 : 0;
        float fy0 = (y0 <= FM_H - 1) ? 1.0f : 0.0f;

        unsigned a0 = (unsigned)(rowoff * FM_W + x0);   // 10 bits
        unsigned meta = a0 | ((unsigned)dx << 10) | ((unsigned)dy << 11)
                      | ((unsigned)k << 12);

        int rank = atomicAdd(&lcnt[q], 1);
        if (rank < BUCKET_CAP) {
            float4 r;
            r.x = __uint_as_float(meta);
            r.y = wx;
            r.z = (1.0f - wy) * fy0;
            r.w = wy * (float)dy;
            bucket[(size_t)(b * QSTRIPS + q) * BUCKET_CAP + rank] = r;
        }
    }
    __syncthreads();
    if (tid < QSTRIPS) counts[b * QSTRIPS + tid] = min(lcnt[tid], BUCKET_CAP);
}

// ---------------------------------------------------------------------------
// Kernel 2: BEV gather, wave-asynchronous strips. 1024 blocks (one/plane),
// 256 threads. Wave w owns strips [10w, 10w+10): stage strip s+2 -> its
// private LDS buffer while scanning strip s; sync with per-wave counted
// vmcnt(5) only (5 GLL/strip). All strips of a plane run CONCURRENTLY
// (4 waves interleaved) so output-line writes cluster in time and L2 merges
// them (R1/R3 evidence: WRITE ~= ideal), unlike R4's sequential phases.
// ---------------------------------------------------------------------------
__global__ __launch_bounds__(256) void bev_kernel(
    const float* __restrict__ fm,          // [B, C, H, W]
    const int* __restrict__ counts,        // [160]
    const float4* __restrict__ bucket,     // [160 * BUCKET_CAP]
    float* __restrict__ out_bev)           // [B, C, K]
{
    __shared__ float lds[WAVES][2][BUF_V4 * 4];   // 40960 B

    const int tid  = threadIdx.x;
    const int lane = tid & 63;
    const int wid  = tid >> 6;
    const int plane = blockIdx.x;
    const int b = plane >> 8;                     // / CHANNELS
    const float* gsrc = fm + (size_t)plane * PLANE;
    float* outp = out_bev + (size_t)plane * NKP;
    const int s0 = wid * STRIPS_PER_WAVE;

    // Stage strip S into this wave's buffer BUF: exactly 5 GLL/lane (source
    // index clamped for the tail so the vmcnt arithmetic is uniform; dups
    // land in the 320-v4 pad region, never read).
#define STAGE(S, BUF)                                                       \
    {                                                                       \
        const int climit = ((S) == QSTRIPS - 1) ? (STRIP_V4_LAST - 1)       \
                                                : (STRIP_V4 - 1);           \
        const float* src = gsrc + (S) * (ROWS_PER_STRIP * FM_W);            \
        float* dst = &lds[wid][BUF][0];                                     \
        _Pragma("unroll")                                                   \
        for (int it = 0; it < 5; ++it) {                                    \
            int idx = lane + it * 64;                                       \
            int ci = idx > climit ? climit : idx;                           \
            GLL(src + ci * 4, dst + idx * 4);                               \
        }                                                                   \
    }

    STAGE(s0, 0);
    STAGE(s0 + 1, 1);

#pragma unroll
    for (int ls = 0; ls < STRIPS_PER_WAVE; ++ls) {
        const int s = s0 + ls;

        __builtin_amdgcn_sched_barrier(0);
        if (ls == STRIPS_PER_WAVE - 1)
            asm volatile("s_waitcnt vmcnt(0)" ::: "memory");
        else
            asm volatile("s_waitcnt vmcnt(5)" ::: "memory");  // strip s landed
        __builtin_amdgcn_sched_barrier(0);

        const int bq = b * QSTRIPS + s;
        const int cnt = counts[bq];
        const float4* bk = bucket + (size_t)bq * BUCKET_CAP;
        const float* buf = &lds[wid][ls & 1][0];

        for (int i = lane; i < cnt; i += 64) {
            float4 rr = bk[i];
            unsigned meta = __float_as_uint(rr.x);
            int a0  = meta & 0x3FF;
            int dx  = (meta >> 10) & 1;
            int dyo = ((meta >> 11) & 1) * FM_W;
            int k   = meta >> 12;
            float wx = rr.y, WY0 = rr.z, WY1 = rr.w;
            float v00 = buf[a0];
            float v01 = buf[a0 + dx];
            float v10 = buf[a0 + dyo];
            float v11 = buf[a0 + dyo + dx];
            float ex  = 1.0f - wx;
            float wxm = wx * (float)dx;
            outp[k] = (v00 * ex + v01 * wxm) * WY0
                    + (v10 * ex + v11 * wxm) * WY1;
        }

        // Ensure this strip's ds_reads delivered before overwriting the buffer.
        __builtin_amdgcn_sched_barrier(0);
        asm volatile("s_waitcnt lgkmcnt(0)" ::: "memory");
        __builtin_amdgcn_sched_barrier(0);
        if (ls + 2 < STRIPS_PER_WAVE) STAGE(s + 2, ls & 1);
    }
#undef STAGE
}

// ---------------------------------------------------------------------------
// Kernel 3: box decode, barrier-free register streaming, no LDS -> full
// occupancy. Thread T handles boxes 4T..4T+3 (14 dwordx4 loads; L1 absorbs
// the stride-112 fan-out), statically-indexed register decode, 7 dwordx4
// stores.
// ---------------------------------------------------------------------------
__global__ __launch_bounds__(256) void decode_kernel(
    const float* __restrict__ deltas,
    const float* __restrict__ anchors,
    float* __restrict__ out_boxes)
{
    const size_t T = (size_t)blockIdx.x * 256 + threadIdx.x;   // < 211200
    const float4* gd = (const float4*)deltas  + T * 7;
    const float4* ga = (const float4*)anchors + T * 7;

    float D[28], A[28];
#pragma unroll
    for (int i = 0; i < 7; ++i) {
        *(float4*)&D[i * 4] = gd[i];
        *(float4*)&A[i * 4] = ga[i];
    }

#pragma unroll
    for (int m = 0; m < 4; ++m) {
        const int o = m * 7;
        float aw = A[o + 3], al = A[o + 4], ah = A[o + 5];
        float dn = sqrtf(aw * aw + al * al);
        float r0 = D[o + 0] * dn + A[o + 0];
        float r1 = D[o + 1] * dn + A[o + 1];
        float r2 = D[o + 2] * ah + A[o + 2];
        float r3 = expf(D[o + 3]) * aw;
        float r4 = expf(D[o + 4]) * al;
        float r5 = expf(D[o + 5]) * ah;
        float r6 = D[o + 6] + A[o + 6];
        D[o + 0] = r0; D[o + 1] = r1; D[o + 2] = r2; D[o + 3] = r3;
        D[o + 4] = r4; D[o + 5] = r5; D[o + 6] = r6;
    }

    float4* go = (float4*)out_boxes + T * 7;
#pragma unroll
    for (int i = 0; i < 7; ++i) go[i] = *(const float4*)&D[i * 4];
}

extern "C" void kernel_launch(void* const* d_in, const int* in_sizes, int n_in,
                              void* d_out, int out_size, void* d_ws, size_t ws_size,
                              hipStream_t stream)
{
    const float* deltas  = (const float*)d_in[0];
    const float* anchors = (const float*)d_in[1];
    const float* fm      = (const float*)d_in[2];
    const float* kp      = (const float*)d_in[3];

    float* out_boxes = (float*)d_out;
    float* out_bev   = (float*)d_out + BOXES_ELEMS;

    // Workspace: [0,640) counts, [1024, 1024+1.31MB) bucket records.
    int*    counts = (int*)d_ws;
    float4* bucket = (float4*)((char*)d_ws + 1024);

    kp_transform_kernel<<<BATCH, 1024, 0, stream>>>(kp, counts, bucket);

    bev_kernel<<<BATCH * CHANNELS, 256, 0, stream>>>(fm, counts, bucket, out_bev);

    decode_kernel<<<DEC_BLOCKS, 256, 0, stream>>>(deltas, anchors, out_boxes);
}

// Round 7
// 271.699 us; speedup vs baseline: 1.0906x; 1.0906x over previous
//
#include <hip/hip_runtime.h>
#include <math.h>

// Problem constants (from reference)
#define BATCH 4
#define N_ANCHORS 211200
#define CHANNELS 256
#define FM_H 200
#define FM_W 176
#define NKP 4096
#define PLANE (FM_H * FM_W)                   // 35200 floats

#define BOXES_ELEMS (BATCH * N_ANCHORS * 7)   // 5,913,600

// BEV: 50 y-strips of 4 rows; staged strip = 5 rows (overlap row for y+1 tap)
// = 220 float4, padded to 256 (4 GLL/lane). Wave-private double buffer:
// stage = 4 waves * 2 * 4096 B = 32 KB; + 16 KB out-LDS = 48 KB -> 3 blocks/CU.
// Strips per wave: waves 0,1 -> 13, waves 2,3 -> 12.
#define QSTRIPS 50
#define ROWS_PER_STRIP 4
#define STRIP_V4 220                          // 5 rows * 44 float4
#define STRIP_V4_LAST 176                     // strip 49: 4 rows only
#define BUF_V4 256                            // padded per-buffer size (4 GLL)
#define WAVES 4
#define DSTRIDE 4224                          // dense records per batch + pad
#define BEV_BLOCKS (BATCH * CHANNELS)         // 1024

// Decode: barrier-free register streaming, 4 boxes/thread, 1024 boxes/block.
#define DEC_BLOCKS (BATCH * N_ANCHORS / 1024) // 825
#define TOTAL_BLOCKS (BEV_BLOCKS + DEC_BLOCKS)// 1849

// Async global->LDS, 16B/lane (wave-uniform LDS base + lane*16).
#define GLL(g, l) __builtin_amdgcn_global_load_lds(                        \
    (const __attribute__((address_space(1))) void*)(g),                    \
    (__attribute__((address_space(3))) void*)(l), 16, 0, 0)

// ---------------------------------------------------------------------------
// Kernel 1: keypoint transform + DENSE bucketing by strip (counting sort).
// One block per batch (1024 thr, 4 kp/thread). LDS histogram over 50 buckets,
// Hillis-Steele scan, second-pass LDS-atomic ranks -> dense[4096] per batch
// ordered by strip; startcnt[b*50+q] = (start, count). No global atomics.
// Record (16 B): meta = a0 | dx<<10 | dy<<11 | k<<12, wx, WY0, WY1 where
//   a0 = strip-local tap addr (rowoff*176 + x0, rowoff in [0,3], 10 bits)
//   dx = x1-valid (adds 1 col), dy = y1-valid (adds 176)
//   WY0 = (1-wy)*fy0, WY1 = wy*dy (row-valid flags folded into weights).
// Masked taps re-read the unmasked address -> staged garbage never read.
// ---------------------------------------------------------------------------
__global__ __launch_bounds__(1024) void kp_transform_kernel(
    const float* __restrict__ kp,        // [B, K, 3]
    int2* __restrict__ startcnt,         // [B * QSTRIPS]
    float4* __restrict__ dense)          // [B * DSTRIDE]
{
    __shared__ int hist[64];
    __shared__ int scanbuf[64];
    __shared__ int rankc[64];
    __shared__ int startq[64];

    const int b   = blockIdx.x;
    const int tid = threadIdx.x;
    if (tid < 64) { hist[tid] = 0; rankc[tid] = 0; }
    __syncthreads();

    // 4 keypoints = 12 consecutive floats = 3 float4.
    const float4* kp4 = (const float4*)(kp + (size_t)b * NKP * 3) + tid * 3;
    float4 p0 = kp4[0], p1 = kp4[1], p2 = kp4[2];
    float kxJ[4] = {p0.x, p0.w, p1.z, p2.y};
    float kyJ[4] = {p0.y, p1.x, p1.w, p2.z};

    unsigned metaJ[4];
    float wxJ[4], wy0J[4], wy1J[4];
    int qJ[4];

#pragma unroll
    for (int j = 0; j < 4; ++j) {
        const int k = tid * 4 + j;
        // Verbatim transform math (keeps absmax behavior).
        float ix_idx = kxJ[j] / 0.4f;
        float iy_idx = (kyJ[j] + 40.0f) / 0.4f;
        ix_idx = fminf(fmaxf(ix_idx, 0.0f), (float)(FM_W - 1));
        iy_idx = fminf(fmaxf(iy_idx, 0.0f), (float)(FM_H - 1));
        float nx = 2.0f * (ix_idx / (float)(FM_W - 2)) - 1.0f;
        float ny = 2.0f * (iy_idx / (float)(FM_H - 2)) - 1.0f;
        // grid flip: width coord gets ny, height coord gets nx
        float ix = (ny + 1.0f) * 0.5f * (float)(FM_W - 1);
        float iy = (nx + 1.0f) * 0.5f * (float)(FM_H - 1);

        float x0f = floorf(ix);
        float y0f = floorf(iy);
        float wx = ix - x0f;
        float wy = iy - y0f;
        int x0 = (int)x0f;      // in [0, 175]
        int y0 = (int)y0f;      // in [0, 200] (200 = fully masked row)

        int q = min(y0 / ROWS_PER_STRIP, QSTRIPS - 1);
        int yc0 = min(y0, FM_H - 1);
        int rowoff = yc0 - q * ROWS_PER_STRIP;          // [0, 3]
        int dx = (x0 + 1 <= FM_W - 1) ? 1 : 0;
        int dy = (y0 + 1 <= FM_H - 1) ? 1 : 0;
        float fy0 = (y0 <= FM_H - 1) ? 1.0f : 0.0f;

        unsigned a0 = (unsigned)(rowoff * FM_W + x0);   // <= 703, 10 bits
        metaJ[j] = a0 | ((unsigned)dx << 10) | ((unsigned)dy << 11)
                 | ((unsigned)k << 12);
        wxJ[j]  = wx;
        wy0J[j] = (1.0f - wy) * fy0;
        wy1J[j] = wy * (float)dy;
        qJ[j]   = q;
        atomicAdd(&hist[q], 1);
    }
    __syncthreads();

    // Inclusive scan of hist[0..63] (Hillis-Steele, 64 lanes active).
    int v = (tid < 64) ? hist[tid] : 0;
#pragma unroll
    for (int d = 1; d < 64; d <<= 1) {
        if (tid < 64) scanbuf[tid] = v;
        __syncthreads();
        if (tid < 64 && tid >= d) v += scanbuf[tid - d];
        __syncthreads();
    }
    if (tid < 64) {
        int c  = hist[tid];
        int st = v - c;
        startq[tid] = st;
        if (tid < QSTRIPS) startcnt[b * QSTRIPS + tid] = make_int2(st, c);
    }
    __syncthreads();

#pragma unroll
    for (int j = 0; j < 4; ++j) {
        int q = qJ[j];
        int r = atomicAdd(&rankc[q], 1);
        float4 rec;
        rec.x = __uint_as_float(metaJ[j]);
        rec.y = wxJ[j];
        rec.z = wy0J[j];
        rec.w = wy1J[j];
        dense[(size_t)b * DSTRIDE + startq[q] + r] = rec;
    }
}

// ---------------------------------------------------------------------------
// Kernel 2: fused bev + decode.
// bev block: wave w owns strips [sb, sb+nS). Per strip s (steady state):
//   issue [startcnt(s+1) -> GLL(s+1)x4 -> rec(s+1)x2]  then  vmcnt(6)
//   -> scan strip s ENTIRELY from regs+LDS (taps from stage buf, result into
//      out-LDS): the scan issues ZERO VMEM ops, so the s+1 prefetch stays in
//      flight (vmcnt retires in order; R5's scan loads/stores were silently
//      draining the prefetch every strip).
// Output accumulates in a 16 KB out-LDS, flushed densely at block end ->
// HBM writes are perfectly coalesced regardless of record order (fixes the
// 7.5x write amplification seen in R4/R5).
// dec block: barrier-free register streaming (4 boxes/thread).
// ---------------------------------------------------------------------------
__global__ __launch_bounds__(256, 3) void fused_kernel(
    const float* __restrict__ deltas,
    const float* __restrict__ anchors,
    const float* __restrict__ fm,          // [B, C, H, W]
    const int2* __restrict__ startcnt,     // [B * QSTRIPS]
    const float4* __restrict__ dense,      // [B * DSTRIDE]
    float* __restrict__ out_boxes,
    float* __restrict__ out_bev)           // [B, C, K]
{
    __shared__ float stage[WAVES][2][BUF_V4 * 4];   // 32768 B
    __shared__ float outl[NKP];                     // 16384 B

    const int tid = threadIdx.x;
    const int bid = blockIdx.x;

    // ---- role mapping: 1:1 interleave for 825 pairs, then bev tail ----
    bool isDec;
    int idx;
    if (bid < 2 * DEC_BLOCKS) { isDec = (bid & 1); idx = bid >> 1; }
    else                      { isDec = false;     idx = DEC_BLOCKS + (bid - 2 * DEC_BLOCKS); }

    if (!isDec) {
        // ---- BEV plane block ----
        const int lane = tid & 63;
        const int wid  = tid >> 6;
        const int plane = idx;
        const int b = plane >> 8;                   // / CHANNELS
        const float* gsrc = fm + (size_t)plane * PLANE;

        const int sb = (wid < 2) ? wid * 13 : 26 + (wid - 2) * 12;
        const int nS = (wid < 2) ? 13 : 12;
        const float4* dbase = dense + (size_t)b * DSTRIDE;
        const int2* scb = startcnt + b * QSTRIPS;

        // Stage strip S -> wave buffer BUF: exactly 4 GLL/lane (tail source
        // clamped -> uniform vmcnt arithmetic; dups land in pad, never read).
#define STAGE(S, BUF)                                                       \
        {                                                                   \
            const int climit = ((S) == QSTRIPS - 1) ? (STRIP_V4_LAST - 1)   \
                                                    : (STRIP_V4 - 1);       \
            const float* src = gsrc + (S) * (ROWS_PER_STRIP * FM_W);        \
            float* dst = &stage[wid][BUF][0];                               \
            _Pragma("unroll")                                               \
            for (int it = 0; it < 4; ++it) {                                \
                int i4 = lane + it * 64;                                    \
                int ci = i4 > climit ? climit : i4;                         \
                GLL(src + ci * 4, dst + i4 * 4);                            \
            }                                                               \
        }

#define PROC(rr)                                                            \
        {                                                                   \
            unsigned meta = __float_as_uint((rr).x);                        \
            int a0  = meta & 0x3FF;                                         \
            int dxb = (meta >> 10) & 1;                                     \
            int dyo = ((meta >> 11) & 1) * FM_W;                            \
            int k   = meta >> 12;                                           \
            float wx = (rr).y, WY0 = (rr).z, WY1 = (rr).w;                  \
            float v00 = buf[a0];                                            \
            float v01 = buf[a0 + dxb];                                      \
            float v10 = buf[a0 + dyo];                                      \
            float v11 = buf[a0 + dyo + dxb];                                \
            float exf = 1.0f - wx;                                          \
            float wxm = wx * (float)dxb;                                    \
            outl[k] = (v00 * exf + v01 * wxm) * WY0                         \
                    + (v10 * exf + v11 * wxm) * WY1;                        \
        }

        // Prologue: stage strip sb + preload its records (order: GLL, recs).
        int2 sc = scb[sb];
        STAGE(sb, 0);
        const float4* bk = dbase + sc.x;
        float4 rA = bk[lane];
        float4 rB = bk[lane + 64];
        int cnt = sc.y;

#pragma unroll 1
        for (int ls = 0; ls < nS; ++ls) {
            const int s = sb + ls;
            const float4* bkN = bk;
            float4 rA2 = rA, rB2 = rB;
            int cntN = 0;

            if (ls + 1 < nS) {
                int2 scN = scb[s + 1];
                STAGE(s + 1, (ls + 1) & 1);
                bkN = dbase + scN.x;
                rA2 = bkN[lane];
                rB2 = bkN[lane + 64];
                cntN = scN.y;
                __builtin_amdgcn_sched_barrier(0);
                // retire strip s's 4 GLL + 2 rec loads; keep s+1's 6 in flight
                asm volatile("s_waitcnt vmcnt(6)" ::: "memory");
            } else {
                __builtin_amdgcn_sched_barrier(0);
                asm volatile("s_waitcnt vmcnt(0)" ::: "memory");
            }
            __builtin_amdgcn_sched_barrier(0);

            // Scan strip s: zero VMEM issued (regs + LDS only).
            const float* buf = &stage[wid][ls & 1][0];
            if (lane < cnt)      PROC(rA);
            if (lane + 64 < cnt) PROC(rB);
            for (int i = 128 + lane; i < cnt; i += 64) {   // rare overflow
                float4 rr = bk[i];
                PROC(rr);
            }

            bk = bkN; rA = rA2; rB = rB2; cnt = cntN;
        }
#undef STAGE
#undef PROC

        // Dense coalesced flush of the plane's 16 KB output.
        __syncthreads();
        float4* go = (float4*)(out_bev + (size_t)plane * NKP);
        const float4* lo = (const float4*)outl;
#pragma unroll
        for (int it = 0; it < 4; ++it)
            go[tid + it * 256] = lo[tid + it * 256];
    } else {
        // ---- decode: 4 boxes/thread in registers, no LDS, no barriers ----
        const size_t T = (size_t)idx * 256 + tid;          // < 211200
        const float4* gd = (const float4*)deltas  + T * 7;
        const float4* ga = (const float4*)anchors + T * 7;

        float D[28], A[28];
#pragma unroll
        for (int i = 0; i < 7; ++i) {
            *(float4*)&D[i * 4] = gd[i];
            *(float4*)&A[i * 4] = ga[i];
        }

#pragma unroll
        for (int m = 0; m < 4; ++m) {
            const int o = m * 7;
            float aw = A[o + 3], al = A[o + 4], ah = A[o + 5];
            float dn = sqrtf(aw * aw + al * al);
            float r0 = D[o + 0] * dn + A[o + 0];
            float r1 = D[o + 1] * dn + A[o + 1];
            float r2 = D[o + 2] * ah + A[o + 2];
            float r3 = expf(D[o + 3]) * aw;
            float r4 = expf(D[o + 4]) * al;
            float r5 = expf(D[o + 5]) * ah;
            float r6 = D[o + 6] + A[o + 6];
            D[o + 0] = r0; D[o + 1] = r1; D[o + 2] = r2; D[o + 3] = r3;
            D[o + 4] = r4; D[o + 5] = r5; D[o + 6] = r6;
        }

        float4* go = (float4*)out_boxes + T * 7;
#pragma unroll
        for (int i = 0; i < 7; ++i) go[i] = *(const float4*)&D[i * 4];
    }
}

extern "C" void kernel_launch(void* const* d_in, const int* in_sizes, int n_in,
                              void* d_out, int out_size, void* d_ws, size_t ws_size,
                              hipStream_t stream)
{
    const float* deltas  = (const float*)d_in[0];
    const float* anchors = (const float*)d_in[1];
    const float* fm      = (const float*)d_in[2];
    const float* kp      = (const float*)d_in[3];

    float* out_boxes = (float*)d_out;
    float* out_bev   = (float*)d_out + BOXES_ELEMS;

    // Workspace: [0, 1600) startcnt (200 int2), [8192, 8192+270336) dense.
    int2*   startcnt = (int2*)d_ws;
    float4* dense    = (float4*)((char*)d_ws + 8192);

    kp_transform_kernel<<<BATCH, 1024, 0, stream>>>(kp, startcnt, dense);

    fused_kernel<<<TOTAL_BLOCKS, 256, 0, stream>>>(
        deltas, anchors, fm, startcnt, dense, out_boxes, out_bev);
}